// Round 1
// baseline (153.751 us; speedup 1.0000x reference)
//
#include <hip/hip_runtime.h>
#include <hip/hip_bf16.h>

typedef __attribute__((ext_vector_type(8))) short short8;
typedef __attribute__((ext_vector_type(4))) float f32x4;

#define C_ 128

__device__ __forceinline__ float b2f(short s) {
    unsigned int u = ((unsigned int)(unsigned short)s) << 16;
    return __builtin_bit_cast(float, u);
}
__device__ __forceinline__ short f2b(float f) {
    __hip_bfloat16 h = __float2bfloat16(f);
    return __builtin_bit_cast(short, h);
}
__device__ __forceinline__ float prelu_f(float x, float s) {
    return fmaxf(x, 0.f) + s * fminf(x, 0.f);
}

// One block per graph. 256 threads = 4 waves.
// Phases:
//  P0  load x1,x2 tiles -> LDS (f32, [32][132] padded)
//  P1  r1,r2 readouts + tv = a*inter[g]
//  P45 ug = Wm3^T tv, cbias = bm3.tv
//  P2  gating MLPs via bf16 MFMA -> w1,w2 per node
//  P3  scale x by w in LDS; keep per-thread register slices for xi/xj stores
//  P4  U = prelu(x1g)@Wm1_top + bm1, V = prelu(x2g)@Wm1_bot  (bf16 MFMA),
//      stored bf16 into LDS (aliasing xs) with rotation swizzle
//  P5  per pair-tile: A = prelu(U[i]+V[j], pm1) -> MFMA @ Wm2 -> epilogue
//      prelu(.,pm2).ug accumulate; xi/xj stores interleaved 4 per iteration
__global__ __launch_bounds__(256, 1) void interactions_fused(
    const float* __restrict__ x1_, const float* __restrict__ x2_,
    const float* __restrict__ inter, const float* __restrict__ aP,
    const float* __restrict__ Wm1, const float* __restrict__ bm1,
    const float* __restrict__ Wm2, const float* __restrict__ bm2,
    const float* __restrict__ Wm3, const float* __restrict__ bm3,
    const float* __restrict__ pm0p, const float* __restrict__ pm1p,
    const float* __restrict__ pm2p,
    const float* __restrict__ Wg1a, const float* __restrict__ bg1a,
    const float* __restrict__ Wg1b, const float* __restrict__ bg1b,
    const float* __restrict__ pw1p,
    const float* __restrict__ Wg2a, const float* __restrict__ bg2a,
    const float* __restrict__ Wg2b, const float* __restrict__ bg2b,
    const float* __restrict__ pw2p,
    float* __restrict__ out)
{
    __shared__ __align__(16) unsigned char regA[33792];  // xs1|xs2, later Ub|Vb
    __shared__ __align__(16) float rr[2][C_];
    __shared__ __align__(16) float tv[C_];
    __shared__ __align__(16) float ugs[C_];
    __shared__ float wgt[2][32];
    __shared__ float red[4];
    __shared__ float cbias_s;

    const int t = threadIdx.x;
    const int g = blockIdx.x;
    const int lane = t & 63;
    const int w = t >> 6;
    float* xs1 = (float*)regA;                 // [32][132] f32
    float* xs2 = (float*)(regA + 16896);

    // ---------------- P0: load x tiles ----------------
    {
        const float* s1 = x1_ + (size_t)g * 4096;
        const float* s2 = x2_ + (size_t)g * 4096;
        #pragma unroll
        for (int q = 0; q < 4; ++q) {
            int idx = q * 256 + t;                 // float4 index 0..1023
            int row = idx >> 5, cc = (idx & 31) * 4;
            float4 v1 = *(const float4*)(s1 + idx * 4);
            float4 v2 = *(const float4*)(s2 + idx * 4);
            *(float4*)(xs1 + row * 132 + cc) = v1;
            *(float4*)(xs2 + row * 132 + cc) = v2;
        }
    }
    __syncthreads();

    // ---------------- P1: readouts + tv ----------------
    if (t < 128) {
        float s = 0.f;
        for (int n = 0; n < 32; ++n) s += xs1[n * 132 + t];
        rr[0][t] = s;
        tv[t] = aP[t] * inter[(size_t)g * C_ + t];
    } else {
        int c = t - 128;
        float s = 0.f;
        for (int n = 0; n < 32; ++n) s += xs2[n * 132 + c];
        rr[1][c] = s;
    }
    __syncthreads();

    // ---------------- P4.5: ug, cbias ----------------
    {
        for (int kk = 0; kk < 32; ++kk) {
            int k = w * 32 + kk;
            float p = Wm3[k * C_ + lane] * tv[lane]
                    + Wm3[k * C_ + 64 + lane] * tv[64 + lane];
            #pragma unroll
            for (int m = 1; m < 64; m <<= 1) p += __shfl_xor(p, m);
            if (lane == 0) ugs[k] = p;
        }
        if (w == 0) {
            float p = bm3[lane] * tv[lane] + bm3[64 + lane] * tv[64 + lane];
            #pragma unroll
            for (int m = 1; m < 64; m <<= 1) p += __shfl_xor(p, m);
            if (lane == 0) cbias_s = p;
        }
    }

    // ---------------- P2: gating ----------------
    {
        const int sd = w >> 1;          // 0: side1, 1: side2
        const int rt = w & 1;           // row-tile (nodes 0-15 / 16-31)
        const float* xs = sd ? xs2 : xs1;
        const float* roth = sd ? rr[0] : rr[1];   // side1 concats r2, side2 r1
        const float* Wg  = sd ? Wg2a : Wg1a;
        const float* bga = sd ? bg2a : bg1a;
        const float* wgb = sd ? Wg2b : Wg1b;
        const float bgb = sd ? bg2b[0] : bg1b[0];
        const float pw  = sd ? pw2p[0] : pw1p[0];
        const int row = rt * 16 + (lane & 15);
        const int kg = (lane >> 4) * 8;

        short8 afr[8];
        #pragma unroll
        for (int kt = 0; kt < 8; ++kt) {
            const float* p = (kt < 4) ? (xs + row * 132 + kt * 32 + kg)
                                      : (roth + (kt - 4) * 32 + kg);
            float4 lo = *(const float4*)p;
            float4 hi = *(const float4*)(p + 4);
            short8 fr;
            fr[0] = f2b(lo.x); fr[1] = f2b(lo.y); fr[2] = f2b(lo.z); fr[3] = f2b(lo.w);
            fr[4] = f2b(hi.x); fr[5] = f2b(hi.y); fr[6] = f2b(hi.z); fr[7] = f2b(hi.w);
            afr[kt] = fr;
        }
        float pre0 = 0, pre1 = 0, pre2 = 0, pre3 = 0;
        #pragma unroll
        for (int ct = 0; ct < 8; ++ct) {
            const int c = ct * 16 + (lane & 15);
            f32x4 acc = {0, 0, 0, 0};
            #pragma unroll
            for (int kt = 0; kt < 8; ++kt) {
                const int k = kt * 32 + kg;
                short8 bfr;
                #pragma unroll
                for (int e = 0; e < 8; ++e)
                    bfr[e] = f2b(Wg[(k + e) * C_ + c]);
                acc = __builtin_amdgcn_mfma_f32_16x16x32_bf16(afr[kt], bfr, acc, 0, 0, 0);
            }
            const float bgac = bga[c], wgbc = wgb[c];
            pre0 += prelu_f(acc[0] + bgac, pw) * wgbc;
            pre1 += prelu_f(acc[1] + bgac, pw) * wgbc;
            pre2 += prelu_f(acc[2] + bgac, pw) * wgbc;
            pre3 += prelu_f(acc[3] + bgac, pw) * wgbc;
        }
        float pr[4] = {pre0, pre1, pre2, pre3};
        #pragma unroll
        for (int r = 0; r < 4; ++r) {
            float p = pr[r];
            p += __shfl_xor(p, 1); p += __shfl_xor(p, 2);
            p += __shfl_xor(p, 4); p += __shfl_xor(p, 8);
            if ((lane & 15) == 0)
                wgt[sd][rt * 16 + (lane >> 4) * 4 + r] =
                    1.f / (1.f + __expf(-(p + bgb)));
        }
    }
    __syncthreads();

    // ---------------- P3: scale + register slices ----------------
    float4 sl1[4], sl2[4];
    {
        const int cc = (t & 31) * 4;
        const int tn = t >> 5;
        #pragma unroll
        for (int m = 0; m < 4; ++m) {
            const int nr = m * 8 + tn;
            const float w1v = wgt[0][nr], w2v = wgt[1][nr];
            float4 v1 = *(float4*)(xs1 + nr * 132 + cc);
            float4 v2 = *(float4*)(xs2 + nr * 132 + cc);
            v1.x *= w1v; v1.y *= w1v; v1.z *= w1v; v1.w *= w1v;
            v2.x *= w2v; v2.y *= w2v; v2.z *= w2v; v2.w *= w2v;
            *(float4*)(xs1 + nr * 132 + cc) = v1;
            *(float4*)(xs2 + nr * 132 + cc) = v2;
            sl1[m] = v1; sl2[m] = v2;
        }
    }
    __syncthreads();

    // ---------------- P4: U/V via MFMA, store bf16 swizzled ----------------
    {
        const int sd = w >> 1;
        const int rt = w & 1;
        const float* xs = sd ? xs2 : xs1;
        const float pm0 = pm0p[0];
        const int row = rt * 16 + (lane & 15);
        const int kg = (lane >> 4) * 8;
        short8 afr[4];
        #pragma unroll
        for (int kt = 0; kt < 4; ++kt) {
            const float* p = xs + row * 132 + kt * 32 + kg;
            float4 lo = *(const float4*)p;
            float4 hi = *(const float4*)(p + 4);
            short8 fr;
            fr[0] = f2b(prelu_f(lo.x, pm0)); fr[1] = f2b(prelu_f(lo.y, pm0));
            fr[2] = f2b(prelu_f(lo.z, pm0)); fr[3] = f2b(prelu_f(lo.w, pm0));
            fr[4] = f2b(prelu_f(hi.x, pm0)); fr[5] = f2b(prelu_f(hi.y, pm0));
            fr[6] = f2b(prelu_f(hi.z, pm0)); fr[7] = f2b(prelu_f(hi.w, pm0));
            afr[kt] = fr;
        }
        f32x4 acc[16];
        #pragma unroll
        for (int ct = 0; ct < 16; ++ct) {
            const int c = ct * 16 + (lane & 15);
            f32x4 av = {0, 0, 0, 0};
            #pragma unroll
            for (int kt = 0; kt < 4; ++kt) {
                const int k = kt * 32 + kg;
                short8 bfr;
                #pragma unroll
                for (int e = 0; e < 8; ++e)
                    bfr[e] = f2b(Wm1[(size_t)(sd * 128 + k + e) * 256 + c]);
                av = __builtin_amdgcn_mfma_f32_16x16x32_bf16(afr[kt], bfr, av, 0, 0, 0);
            }
            acc[ct] = av;
        }
        __syncthreads();   // all xs reads complete before aliasing writes
        unsigned char* dst = regA + (sd ? 16896 : 0);   // Ub at 0, Vb at 16896
        #pragma unroll
        for (int ct = 0; ct < 16; ++ct) {
            const int c = ct * 16 + (lane & 15);
            const float badd = sd ? 0.f : bm1[c];   // fold bm1 into U only
            #pragma unroll
            for (int r = 0; r < 4; ++r) {
                const int n = rt * 16 + (lane >> 4) * 4 + r;
                const int off = n * 512 + ((2 * c + ((n & 7) << 6)) & 511);
                *(short*)(dst + off) = f2b(acc[ct][r] + badd);
            }
        }
    }
    __syncthreads();

    // ---------------- P5: pair loop (layer2 MFMA + epilogue + stores) -------
    {
        const float pm1v = pm1p[0], pm2v = pm2p[0];
        const int cl = lane & 15;
        const int c0 = (2 * w) * 16 + cl, c1 = (2 * w + 1) * 16 + cl;
        short8 Bf0[8], Bf1[8];
        #pragma unroll
        for (int kt = 0; kt < 8; ++kt) {
            const int k = kt * 32 + (lane >> 4) * 8;
            short8 b0, b1;
            #pragma unroll
            for (int e = 0; e < 8; ++e) {
                b0[e] = f2b(Wm2[(k + e) * C_ + c0]);
                b1[e] = f2b(Wm2[(k + e) * C_ + c1]);
            }
            Bf0[kt] = b0; Bf1[kt] = b1;
        }
        const float bm2c0 = bm2[c0], bm2c1 = bm2[c1];
        const float ug0 = ugs[c0], ug1 = ugs[c1];
        const unsigned char* Ub = regA;
        const unsigned char* Vb = regA + 16896;
        float* oxi = out + 256 + (size_t)g * 131072;
        float* oxj = out + 256 + 33554432 + (size_t)g * 131072;
        const int cc = (t & 31) * 4;
        const int tn = t >> 5;
        const int kg16 = (lane >> 4) * 16;
        float psum = 0.f;
        #pragma unroll
        for (int rh = 0; rh < 2; ++rh) {
            for (int rt2 = 0; rt2 < 32; ++rt2) {
                const int rt = rh * 32 + rt2;
                const int i = rt >> 1;                       // uniform per instr
                const int j = ((rt & 1) << 4) + cl;          // per-lane row of V
                const int ub = i * 512, us = (i & 7) << 6;
                const int vb = j * 512, vs = (j & 7) << 6;
                f32x4 acc0 = {0, 0, 0, 0}, acc1 = {0, 0, 0, 0};
                #pragma unroll
                for (int kt = 0; kt < 8; ++kt) {
                    const int koff = kt * 64 + kg16;
                    short8 u8 = *(const short8*)(Ub + ub + ((koff + us) & 511));
                    short8 v8 = *(const short8*)(Vb + vb + ((koff + vs) & 511));
                    short8 af;
                    #pragma unroll
                    for (int e = 0; e < 8; ++e)
                        af[e] = f2b(prelu_f(b2f(u8[e]) + b2f(v8[e]), pm1v));
                    acc0 = __builtin_amdgcn_mfma_f32_16x16x32_bf16(af, Bf0[kt], acc0, 0, 0, 0);
                    acc1 = __builtin_amdgcn_mfma_f32_16x16x32_bf16(af, Bf1[kt], acc1, 0, 0, 0);
                }
                #pragma unroll
                for (int r = 0; r < 4; ++r) {
                    psum += prelu_f(acc0[r] + bm2c0, pm2v) * ug0;
                    psum += prelu_f(acc1[r] + bm2c1, pm2v) * ug1;
                }
                // interleaved xi/xj stores (4 per iteration, covers all 256)
                const int jj = rt2;
                const int n0 = (rh * 2) * 8 + tn;
                const int n1 = (rh * 2 + 1) * 8 + tn;
                *(float4*)(oxi + (size_t)(n0 * 32 + jj) * 128 + cc) = sl1[rh * 2];
                *(float4*)(oxi + (size_t)(n1 * 32 + jj) * 128 + cc) = sl1[rh * 2 + 1];
                *(float4*)(oxj + (size_t)(jj * 32 + n0) * 128 + cc) = sl2[rh * 2];
                *(float4*)(oxj + (size_t)(jj * 32 + n1) * 128 + cc) = sl2[rh * 2 + 1];
            }
        }
        #pragma unroll
        for (int m = 1; m < 64; m <<= 1) psum += __shfl_xor(psum, m);
        if (lane == 0) red[w] = psum;
    }
    __syncthreads();
    if (t == 0)
        out[g] = red[0] + red[1] + red[2] + red[3] + 1024.f * cbias_s;
}

extern "C" void kernel_launch(void* const* d_in, const int* in_sizes, int n_in,
                              void* d_out, int out_size, void* d_ws, size_t ws_size,
                              hipStream_t stream) {
    const float* x1   = (const float*)d_in[0];
    const float* x2   = (const float*)d_in[1];
    const float* itr  = (const float*)d_in[2];
    // d_in[3..7]: batch_1, batch_2, ind_1, ind_2, batch_ans — structure is
    // closed-form (32 nodes/graph): not needed on device.
    const float* a    = (const float*)d_in[8];
    const float* Wm1  = (const float*)d_in[9];
    const float* bm1  = (const float*)d_in[10];
    const float* Wm2  = (const float*)d_in[11];
    const float* bm2  = (const float*)d_in[12];
    const float* Wm3  = (const float*)d_in[13];
    const float* bm3  = (const float*)d_in[14];
    const float* pm0  = (const float*)d_in[15];
    const float* pm1  = (const float*)d_in[16];
    const float* pm2  = (const float*)d_in[17];
    const float* Wg1a = (const float*)d_in[18];
    const float* bg1a = (const float*)d_in[19];
    const float* Wg1b = (const float*)d_in[20];
    const float* bg1b = (const float*)d_in[21];
    const float* pw1  = (const float*)d_in[22];
    const float* Wg2a = (const float*)d_in[23];
    const float* bg2a = (const float*)d_in[24];
    const float* Wg2b = (const float*)d_in[25];
    const float* bg2b = (const float*)d_in[26];
    const float* pw2  = (const float*)d_in[27];
    float* out = (float*)d_out;

    hipLaunchKernelGGL(interactions_fused, dim3(256), dim3(256), 0, stream,
                       x1, x2, itr, a, Wm1, bm1, Wm2, bm2, Wm3, bm3,
                       pm0, pm1, pm2, Wg1a, bg1a, Wg1b, bg1b, pw1,
                       Wg2a, bg2a, Wg2b, bg2b, pw2, out);
}

// Round 3
// 86.994 us; speedup vs baseline: 1.7674x; 1.7674x over previous
//
#include <hip/hip_runtime.h>
#include <hip/hip_bf16.h>
#include <hip/hip_fp16.h>

typedef __attribute__((ext_vector_type(8))) _Float16 half8;
typedef __attribute__((ext_vector_type(2))) _Float16 f16x2;
typedef __attribute__((ext_vector_type(4))) float f32x4;

#define C_ 128

__device__ __forceinline__ unsigned short f2h(float f) {
    return __builtin_bit_cast(unsigned short, (_Float16)f);
}
__device__ __forceinline__ f16x2 pkrtz(float x, float y) {
    return __builtin_bit_cast(f16x2, __builtin_amdgcn_cvt_pkrtz(x, y));
}
__device__ __forceinline__ float prelu_f(float x, float s) {
    return fmaxf(x, 0.f) + s * fminf(x, 0.f);
}
// packed-f16 prelu: max(x,0) + s*min(x,0) via v_pk ops
__device__ __forceinline__ half8 prelu_h8(half8 x, half8 sl) {
    half8 z = {0, 0, 0, 0, 0, 0, 0, 0};
    half8 mx = __builtin_elementwise_max(x, z);
    half8 mn = __builtin_elementwise_min(x, z);
    return mx + mn * sl;
}

// ---- K0: convert + transpose weights to f16 in d_ws ----
// ws layout (shorts): [0]      Wm1T [c 256][k 256]
//                     [65536]  Wm2T [c 128][k 256]
//                     [98304]  Wg1aT[c 128][k 256]
//                     [131072] Wg2aT[c 128][k 256]
__global__ __launch_bounds__(256) void prep_weights(
    const float* __restrict__ Wm1, const float* __restrict__ Wm2,
    const float* __restrict__ Wg1a, const float* __restrict__ Wg2a,
    short* __restrict__ ws)
{
    int tid = blockIdx.x * 256 + threadIdx.x;
    if (tid < 65536) {                       // Wm1 [k 256][c 256], coalesced read
        int k = tid >> 8, c = tid & 255;
        ws[c * 256 + k] = (short)f2h(Wm1[tid]);
    }
    if (tid < 32768) {                       // [k 256][c 128] arrays
        int k = tid >> 7, c = tid & 127;
        ws[65536  + c * 256 + k] = (short)f2h(Wm2[tid]);
        ws[98304  + c * 256 + k] = (short)f2h(Wg1a[tid]);
        ws[131072 + c * 256 + k] = (short)f2h(Wg2a[tid]);
    }
}

// One block per graph, 256 threads = 4 waves.
__global__ __launch_bounds__(256, 1) void interactions_fused(
    const float* __restrict__ x1_, const float* __restrict__ x2_,
    const float* __restrict__ inter, const float* __restrict__ aP,
    const short* __restrict__ Wt,
    const float* __restrict__ bm1, const float* __restrict__ bm2,
    const float* __restrict__ Wm3, const float* __restrict__ bm3,
    const float* __restrict__ pm0p, const float* __restrict__ pm1p,
    const float* __restrict__ pm2p,
    const float* __restrict__ bg1a, const float* __restrict__ Wg1b,
    const float* __restrict__ bg1b, const float* __restrict__ pw1p,
    const float* __restrict__ bg2a, const float* __restrict__ Wg2b,
    const float* __restrict__ bg2b, const float* __restrict__ pw2p,
    float* __restrict__ out)
{
    __shared__ __align__(16) unsigned char regA[33792];  // xs1|xs2, later Ub|Vb
    __shared__ __align__(16) float rr[2][C_];
    __shared__ __align__(16) float tv[C_];
    __shared__ __align__(16) float ugs[C_];
    __shared__ float wgt[2][32];
    __shared__ float red[4];
    __shared__ float cbias_s;

    const int t = threadIdx.x;
    const int g = blockIdx.x;
    const int lane = t & 63;
    const int w = t >> 6;
    float* xs1 = (float*)regA;                 // [32][132] f32
    float* xs2 = (float*)(regA + 16896);

    // ---------------- P0: load x tiles ----------------
    {
        const float* s1 = x1_ + (size_t)g * 4096;
        const float* s2 = x2_ + (size_t)g * 4096;
        #pragma unroll
        for (int q = 0; q < 4; ++q) {
            int idx = q * 256 + t;
            int row = idx >> 5, cc = (idx & 31) * 4;
            float4 v1 = *(const float4*)(s1 + idx * 4);
            float4 v2 = *(const float4*)(s2 + idx * 4);
            *(float4*)(xs1 + row * 132 + cc) = v1;
            *(float4*)(xs2 + row * 132 + cc) = v2;
        }
    }
    __syncthreads();

    // ---------------- P1: readouts + tv ----------------
    if (t < 128) {
        float s = 0.f;
        for (int n = 0; n < 32; ++n) s += xs1[n * 132 + t];
        rr[0][t] = s;
        tv[t] = aP[t] * inter[(size_t)g * C_ + t];
    } else {
        int c = t - 128;
        float s = 0.f;
        for (int n = 0; n < 32; ++n) s += xs2[n * 132 + c];
        rr[1][c] = s;
    }
    __syncthreads();

    // ---------------- ug[c] = dot(Wm3 row c, tv); cbias = bm3.tv ----------
    if (t < 128) {
        const float* wr = Wm3 + t * C_;
        float s0 = 0, s1 = 0, s2 = 0, s3 = 0;
        #pragma unroll
        for (int k = 0; k < 128; k += 4) {
            float4 wv = *(const float4*)(wr + k);
            s0 += wv.x * tv[k];     s1 += wv.y * tv[k + 1];
            s2 += wv.z * tv[k + 2]; s3 += wv.w * tv[k + 3];
        }
        ugs[t] = (s0 + s1) + (s2 + s3);
    } else if (t < 192) {   // wave 2
        float p = bm3[lane] * tv[lane] + bm3[64 + lane] * tv[64 + lane];
        #pragma unroll
        for (int m = 1; m < 64; m <<= 1) p += __shfl_xor(p, m);
        if (lane == 0) cbias_s = p;
    }

    // ---------------- P2: gating (f16 MFMA) ----------------
    {
        const int sd = w >> 1;
        const int rt = w & 1;
        const float* xs = sd ? xs2 : xs1;
        const float* roth = sd ? rr[0] : rr[1];
        const short* WgT = Wt + (sd ? 131072 : 98304);
        const float* bga = sd ? bg2a : bg1a;
        const float* wgb = sd ? Wg2b : Wg1b;
        const float bgb = sd ? bg2b[0] : bg1b[0];
        const float pw  = sd ? pw2p[0] : pw1p[0];
        const int row = rt * 16 + (lane & 15);
        const int kg = (lane >> 4) * 8;

        half8 afr[8];
        #pragma unroll
        for (int kt = 0; kt < 8; ++kt) {
            const float* p = (kt < 4) ? (xs + row * 132 + kt * 32 + kg)
                                      : (roth + (kt - 4) * 32 + kg);
            float4 lo = *(const float4*)p;
            float4 hi = *(const float4*)(p + 4);
            f16x2 a = pkrtz(lo.x, lo.y);
            f16x2 b = pkrtz(lo.z, lo.w);
            f16x2 c = pkrtz(hi.x, hi.y);
            f16x2 d = pkrtz(hi.z, hi.w);
            half8 fr = {a[0], a[1], b[0], b[1], c[0], c[1], d[0], d[1]};
            afr[kt] = fr;
        }
        float pr[4] = {0, 0, 0, 0};
        #pragma unroll
        for (int ct = 0; ct < 8; ++ct) {
            const int c = ct * 16 + (lane & 15);
            const short* wp = WgT + c * 256 + kg;
            f32x4 acc = {0, 0, 0, 0};
            #pragma unroll
            for (int kt = 0; kt < 8; ++kt)
                acc = __builtin_amdgcn_mfma_f32_16x16x32_f16(
                          afr[kt], *(const half8*)(wp + kt * 32), acc, 0, 0, 0);
            const float bgac = bga[c], wgbc = wgb[c];
            #pragma unroll
            for (int r = 0; r < 4; ++r)
                pr[r] += prelu_f(acc[r] + bgac, pw) * wgbc;
        }
        #pragma unroll
        for (int r = 0; r < 4; ++r) {
            float p = pr[r];
            p += __shfl_xor(p, 1); p += __shfl_xor(p, 2);
            p += __shfl_xor(p, 4); p += __shfl_xor(p, 8);
            if ((lane & 15) == 0)
                wgt[sd][rt * 16 + (lane >> 4) * 4 + r] =
                    1.f / (1.f + __expf(-(p + bgb)));
        }
    }
    __syncthreads();

    // ---------------- P3: scale + register slices ----------------
    float4 sl1[4], sl2[4];
    {
        const int cc = (t & 31) * 4;
        const int tn = t >> 5;
        #pragma unroll
        for (int m = 0; m < 4; ++m) {
            const int nr = m * 8 + tn;
            const float w1v = wgt[0][nr], w2v = wgt[1][nr];
            float4 v1 = *(float4*)(xs1 + nr * 132 + cc);
            float4 v2 = *(float4*)(xs2 + nr * 132 + cc);
            v1.x *= w1v; v1.y *= w1v; v1.z *= w1v; v1.w *= w1v;
            v2.x *= w2v; v2.y *= w2v; v2.z *= w2v; v2.w *= w2v;
            *(float4*)(xs1 + nr * 132 + cc) = v1;
            *(float4*)(xs2 + nr * 132 + cc) = v2;
            sl1[m] = v1; sl2[m] = v2;
        }
    }
    __syncthreads();

    // ---------------- P4: U/V via f16 MFMA, store f16 swizzled ----------
    {
        const int sd = w >> 1;
        const int rt = w & 1;
        const float* xs = sd ? xs2 : xs1;
        const float pm0 = pm0p[0];
        const int row = rt * 16 + (lane & 15);
        const int kg = (lane >> 4) * 8;
        half8 afr[4];
        #pragma unroll
        for (int kt = 0; kt < 4; ++kt) {
            const float* p = xs + row * 132 + kt * 32 + kg;
            float4 lo = *(const float4*)p;
            float4 hi = *(const float4*)(p + 4);
            f16x2 a = pkrtz(prelu_f(lo.x, pm0), prelu_f(lo.y, pm0));
            f16x2 b = pkrtz(prelu_f(lo.z, pm0), prelu_f(lo.w, pm0));
            f16x2 c = pkrtz(prelu_f(hi.x, pm0), prelu_f(hi.y, pm0));
            f16x2 d = pkrtz(prelu_f(hi.z, pm0), prelu_f(hi.w, pm0));
            half8 fr = {a[0], a[1], b[0], b[1], c[0], c[1], d[0], d[1]};
            afr[kt] = fr;
        }
        f32x4 acc[16];
        #pragma unroll
        for (int ct = 0; ct < 16; ++ct) {
            const int c = ct * 16 + (lane & 15);
            const short* wp = Wt + c * 256 + sd * 128 + kg;   // Wm1T
            f32x4 av = {0, 0, 0, 0};
            #pragma unroll
            for (int kt = 0; kt < 4; ++kt)
                av = __builtin_amdgcn_mfma_f32_16x16x32_f16(
                         afr[kt], *(const half8*)(wp + kt * 32), av, 0, 0, 0);
            acc[ct] = av;
        }
        __syncthreads();   // xs reads complete before aliasing writes
        unsigned char* dst = regA + (sd ? 16896 : 0);   // Ub at 0, Vb at 16896
        #pragma unroll
        for (int ct = 0; ct < 16; ++ct) {
            const int c = ct * 16 + (lane & 15);
            const float badd = sd ? 0.f : bm1[c];
            #pragma unroll
            for (int r = 0; r < 4; ++r) {
                const int n = rt * 16 + (lane >> 4) * 4 + r;
                const int off = n * 512 + ((2 * c + ((n & 7) << 6)) & 511);
                *(unsigned short*)(dst + off) = f2h(acc[ct][r] + badd);
            }
        }
    }
    __syncthreads();

    // ---------------- P5: pair loop ----------------
    {
        const float pm1v = pm1p[0], pm2v = pm2p[0];
        const _Float16 pm1s = (_Float16)pm1v;
        const half8 pm1h = {pm1s, pm1s, pm1s, pm1s, pm1s, pm1s, pm1s, pm1s};
        const int cl = lane & 15;
        const int kg8 = (lane >> 4) * 8;
        const int kg16 = kg8 * 2;
        const int c0 = (2 * w) * 16 + cl, c1 = (2 * w + 1) * 16 + cl;
        half8 Bf0[8], Bf1[8];
        const short* w2p0 = Wt + 65536 + c0 * 256 + kg8;   // Wm2T
        const short* w2p1 = Wt + 65536 + c1 * 256 + kg8;
        #pragma unroll
        for (int kt = 0; kt < 8; ++kt) {
            Bf0[kt] = *(const half8*)(w2p0 + kt * 32);
            Bf1[kt] = *(const half8*)(w2p1 + kt * 32);
        }
        const float bm2c0 = bm2[c0], bm2c1 = bm2[c1];
        const float ug0 = ugs[c0], ug1 = ugs[c1];
        const unsigned char* Ub = regA;
        const unsigned char* Vb = regA + 16896;

        // hoist V fragments: per lane only j0 = cl and j1 = 16+cl ever occur
        half8 VrA[8], VrB[8];
        {
            const int j0 = cl, j1 = 16 + cl;
            const int vs = (cl & 7) << 6;
            #pragma unroll
            for (int kt = 0; kt < 8; ++kt) {
                const int koff = kt * 64 + kg16;
                VrA[kt] = *(const half8*)(Vb + j0 * 512 + ((koff + vs) & 511));
                VrB[kt] = *(const half8*)(Vb + j1 * 512 + ((koff + ((j1 & 7) << 6)) & 511));
            }
        }

        float* oxi = out + 256 + (size_t)g * 131072;
        float* oxj = out + 256 + 33554432 + (size_t)g * 131072;
        const int cc = (t & 31) * 4;
        const int tn = t >> 5;
        float psum = 0.f;

#define JSET(VR, JJ)                                                          \
        do {                                                                  \
            f32x4 acc0 = {0, 0, 0, 0}, acc1 = {0, 0, 0, 0};                   \
            _Pragma("unroll")                                                 \
            for (int kt = 0; kt < 8; ++kt) {                                  \
                half8 sfull = u8[kt] + VR[kt];                                \
                half8 af = prelu_h8(sfull, pm1h);                             \
                acc0 = __builtin_amdgcn_mfma_f32_16x16x32_f16(af, Bf0[kt], acc0, 0, 0, 0); \
                acc1 = __builtin_amdgcn_mfma_f32_16x16x32_f16(af, Bf1[kt], acc1, 0, 0, 0); \
            }                                                                 \
            _Pragma("unroll")                                                 \
            for (int r = 0; r < 4; ++r) {                                     \
                psum += prelu_f(acc0[r] + bm2c0, pm2v) * ug0;                 \
                psum += prelu_f(acc1[r] + bm2c1, pm2v) * ug1;                 \
            }                                                                 \
            {                                                                 \
                const int jj_ = (JJ);                                         \
                *(float4*)(oxi + (size_t)(n0 * 32 + jj_) * 128 + cc) = s1a;   \
                *(float4*)(oxi + (size_t)(n1 * 32 + jj_) * 128 + cc) = s1b;   \
                *(float4*)(oxj + (size_t)(jj_ * 32 + n0) * 128 + cc) = s2a;   \
                *(float4*)(oxj + (size_t)(jj_ * 32 + n1) * 128 + cc) = s2b;   \
            }                                                                 \
        } while (0)

        #pragma unroll
        for (int rh = 0; rh < 2; ++rh) {
            const int n0 = rh * 16 + tn;
            const int n1 = rh * 16 + 8 + tn;
            const float4 s1a = sl1[rh * 2], s1b = sl1[rh * 2 + 1];
            const float4 s2a = sl2[rh * 2], s2b = sl2[rh * 2 + 1];
            #pragma unroll 2
            for (int ii = 0; ii < 16; ++ii) {
                const int i = rh * 16 + ii;
                const int ub = i * 512, us = (i & 7) << 6;
                half8 u8[8];
                #pragma unroll
                for (int kt = 0; kt < 8; ++kt)
                    u8[kt] = *(const half8*)(Ub + ub + ((kt * 64 + kg16 + us) & 511));
                JSET(VrA, 2 * ii);
                JSET(VrB, 2 * ii + 1);
            }
        }
#undef JSET
        #pragma unroll
        for (int m = 1; m < 64; m <<= 1) psum += __shfl_xor(psum, m);
        if (lane == 0) red[w] = psum;
    }
    __syncthreads();
    if (t == 0)
        out[g] = red[0] + red[1] + red[2] + red[3] + 1024.f * cbias_s;
}

extern "C" void kernel_launch(void* const* d_in, const int* in_sizes, int n_in,
                              void* d_out, int out_size, void* d_ws, size_t ws_size,
                              hipStream_t stream) {
    const float* x1   = (const float*)d_in[0];
    const float* x2   = (const float*)d_in[1];
    const float* itr  = (const float*)d_in[2];
    const float* a    = (const float*)d_in[8];
    const float* Wm1  = (const float*)d_in[9];
    const float* bm1  = (const float*)d_in[10];
    const float* Wm2  = (const float*)d_in[11];
    const float* bm2  = (const float*)d_in[12];
    const float* Wm3  = (const float*)d_in[13];
    const float* bm3  = (const float*)d_in[14];
    const float* pm0  = (const float*)d_in[15];
    const float* pm1  = (const float*)d_in[16];
    const float* pm2  = (const float*)d_in[17];
    const float* Wg1a = (const float*)d_in[18];
    const float* bg1a = (const float*)d_in[19];
    const float* Wg1b = (const float*)d_in[20];
    const float* bg1b = (const float*)d_in[21];
    const float* pw1  = (const float*)d_in[22];
    const float* Wg2a = (const float*)d_in[23];
    const float* bg2a = (const float*)d_in[24];
    const float* Wg2b = (const float*)d_in[25];
    const float* bg2b = (const float*)d_in[26];
    const float* pw2  = (const float*)d_in[27];
    float* out = (float*)d_out;
    short* Wt = (short*)d_ws;   // needs 320 KB

    hipLaunchKernelGGL(prep_weights, dim3(256), dim3(256), 0, stream,
                       Wm1, Wm2, Wg1a, Wg2a, Wt);
    hipLaunchKernelGGL(interactions_fused, dim3(256), dim3(256), 0, stream,
                       x1, x2, itr, a, Wt, bm1, bm2, Wm3, bm3,
                       pm0, pm1, pm2, bg1a, Wg1b, bg1b, pw1,
                       bg2a, Wg2b, bg2b, pw2, out);
}